// Round 2
// baseline (200.006 us; speedup 1.0000x reference)
//
#include <hip/hip_runtime.h>
#include <hip/hip_bf16.h>

typedef __bf16 bf16;
typedef __bf16 bf16x8 __attribute__((ext_vector_type(8)));
typedef float  f32x4  __attribute__((ext_vector_type(4)));

#define MFMA(a, b, c) __builtin_amdgcn_mfma_f32_16x16x32_bf16((a), (b), (c), 0, 0, 0)

// ---------------- prep kernels ----------------

// f32 -> bf16 elementwise (grid-stride, 4 elts/thread)
__global__ void cvt_f32_bf16(const float4* __restrict__ src, ushort4* __restrict__ dst, int n4) {
    for (int i = blockIdx.x * blockDim.x + threadIdx.x; i < n4; i += gridDim.x * blockDim.x) {
        float4 v = src[i];
        ushort4 o;
        o.x = (unsigned short)(__bfloat16_as_ushort(__float2bfloat16(v.x)));
        o.y = (unsigned short)(__bfloat16_as_ushort(__float2bfloat16(v.y)));
        o.z = (unsigned short)(__bfloat16_as_ushort(__float2bfloat16(v.z)));
        o.w = (unsigned short)(__bfloat16_as_ushort(__float2bfloat16(v.w)));
        dst[i] = o;
    }
}

// src[K][N] f32 (row-major) -> dst[N][K] bf16
__global__ void transpose_f32_bf16(const float* __restrict__ src, bf16* __restrict__ dst,
                                   int K, int N) {
    int i = blockIdx.x * 256 + threadIdx.x;
    if (i < K * N) {
        int k = i / N, n = i % N;
        dst[n * K + k] = (bf16)src[i];
    }
}

__global__ void zero_f4(float4* __restrict__ p, int n4) {
    for (int i = blockIdx.x * blockDim.x + threadIdx.x; i < n4; i += gridDim.x * blockDim.x)
        p[i] = make_float4(0.f, 0.f, 0.f, 0.f);
}

// bucket ids: idx[b][t][s], padded to 512x512, sentinel 63 for invalid rows/cols.
// dist >= 0 always (euclidean), so sign==+1 and absd==dist.
__global__ void bucket_kernel(const float* __restrict__ ct, unsigned char* __restrict__ idx) {
    const int b = blockIdx.x >> 9;
    const int t = blockIdx.x & 511;
    const bool tv = (t < 500);
    float ctx = 0.f, cty = 0.f;
    if (tv) {
        ctx = ct[(b * 500 + t) * 2];
        cty = ct[(b * 500 + t) * 2 + 1];
    }
    const int s0 = threadIdx.x * 4;
    uchar4 o;
    unsigned char v[4];
#pragma unroll
    for (int j = 0; j < 4; j++) {
        int s = s0 + j;
        unsigned char r = 63;  // sentinel -> lut_s[63] = -1e30 (mask)
        if (tv && s < 500) {
            float dx = ctx - ct[(b * 500 + s) * 2];
            float dy = cty - ct[(b * 500 + s) * 2 + 1];
            float dist = truncf(sqrtf(dx * dx + dy * dy) / 12.0f);
            int bi;
            if (dist <= 12.0f) {
                bi = (int)dist;
            } else {
                // 12 + ln(d/12)/ln(8) * 12, rounded (half-even), capped at 24
                float lb = fminf(24.0f, rintf(12.0f + (logf(dist / 12.0f) * (1.0f / 2.0794415416798357f)) * 12.0f));
                bi = (int)lb;
            }
            r = (unsigned char)(bi + 24);
        }
        v[j] = r;
    }
    o.x = v[0]; o.y = v[1]; o.z = v[2]; o.w = v[3];
    *(uchar4*)(idx + ((size_t)blockIdx.x) * 512 + s0) = o;
}

// ---------------- GEMM core (shared) ----------------
// C[64x128 block tile] = A[M x 512] * Bt[N x 512]^T, 4 waves (2m x 2n), each wave 32x64.
// A-frag: row = lane&15, k = (lane>>4)*8 + j (contig 8 bf16).  B-frag identical on Bt rows.
// D: col(n) = lane&15, row(m) = (lane>>4)*4 + reg.
__device__ __forceinline__ void gemm_core512(const bf16* __restrict__ Arow0,
                                             const bf16* __restrict__ Brow,
                                             f32x4 (&acc)[2][4]) {
#pragma unroll 4
    for (int k0 = 0; k0 < 512; k0 += 32) {
        bf16x8 a0 = *(const bf16x8*)(Arow0 + k0);
        bf16x8 a1 = *(const bf16x8*)(Arow0 + 16 * 512 + k0);
#pragma unroll
        for (int nf = 0; nf < 4; nf++) {
            bf16x8 bv = *(const bf16x8*)(Brow + (size_t)nf * 16 * 512 + k0);
            acc[0][nf] = MFMA(a0, bv, acc[0][nf]);
            acc[1][nf] = MFMA(a1, bv, acc[1][nf]);
        }
    }
}

// ---------------- QKV GEMM ----------------
// grid (12, 125): x = N-tile(128) over 1536, y = M-tile(64) over 8000.
// Writes q,k as [b][h][512][64] bf16 (t-padded), v transposed as [b][h][64][512].
__global__ __launch_bounds__(256) void qkv_gemm(const bf16* __restrict__ X,
                                                const bf16* __restrict__ Wt,
                                                const float* __restrict__ battn,
                                                bf16* __restrict__ qb,
                                                bf16* __restrict__ kbuf,
                                                bf16* __restrict__ vtb) {
    const int lane = threadIdx.x & 63;
    const int wave = threadIdx.x >> 6;
    const int wr = wave >> 1, wc = wave & 1;
    const int m0 = blockIdx.y * 64 + wr * 32;
    const int n0 = blockIdx.x * 128 + wc * 64;
    const int r = lane & 15;
    const int ko = (lane >> 4) << 3;

    f32x4 acc[2][4];
#pragma unroll
    for (int i = 0; i < 2; i++)
#pragma unroll
        for (int j = 0; j < 4; j++) acc[i][j] = (f32x4){0.f, 0.f, 0.f, 0.f};

    gemm_core512(X + (size_t)(m0 + r) * 512 + ko, Wt + (size_t)(n0 + r) * 512 + ko, acc);

#pragma unroll
    for (int mr = 0; mr < 2; mr++) {
#pragma unroll
        for (int nf = 0; nf < 4; nf++) {
            int n = n0 + nf * 16 + r;
            float bias = battn[n];
#pragma unroll
            for (int reg = 0; reg < 4; reg++) {
                int m = m0 + mr * 16 + ((lane >> 4) << 2) + reg;
                float v = acc[mr][nf][reg] + bias;
                int b = m / 500, t = m - b * 500;
                if (n < 512) {
                    int h = n >> 6, d = n & 63;
                    qb[(((size_t)(b * 8 + h)) * 512 + t) * 64 + d] = (bf16)v;
                } else if (n < 1024) {
                    int n2 = n - 512;
                    int h = n2 >> 6, d = n2 & 63;
                    kbuf[(((size_t)(b * 8 + h)) * 512 + t) * 64 + d] = (bf16)v;
                } else {
                    int n2 = n - 1024;
                    int h = n2 >> 6, d = n2 & 63;
                    vtb[(((size_t)(b * 8 + h)) * 64 + d) * 512 + t] = (bf16)v;
                }
            }
        }
    }
}

// ---------------- fused attention ----------------
// grid 1024: blockIdx.x = (b*8+h)*8 + qtile. 4 waves x 16 q-rows, s-tiles of 64.
__global__ __launch_bounds__(256) void attn_kernel(const bf16* __restrict__ qb,
                                                   const bf16* __restrict__ kbuf,
                                                   const bf16* __restrict__ vtb,
                                                   const unsigned char* __restrict__ idxg,
                                                   const float* __restrict__ lut,
                                                   bf16* __restrict__ yb) {
    const int lane = threadIdx.x & 63;
    const int wave = threadIdx.x >> 6;
    const int bh = blockIdx.x >> 3;  // b*8+h
    const int qt = blockIdx.x & 7;
    const int b = bh >> 3;
    const int h = bh & 7;

    __shared__ float lut_s[64];
    __shared__ __align__(16) bf16 P[4][16][72];  // +8 bf16 pad: 144B row stride (16B-aligned)
    if (threadIdx.x < 64)
        lut_s[threadIdx.x] = (threadIdx.x < 49) ? lut[h * 49 + threadIdx.x] : -1e30f;
    __syncthreads();

    const int r = lane & 15;
    const int ko = (lane >> 4) << 3;
    const int rowbase = qt * 64 + wave * 16;

    const bf16* qp = qb + ((size_t)bh * 512 + rowbase + r) * 64 + ko;
    bf16x8 qf0 = *(const bf16x8*)qp;
    bf16x8 qf1 = *(const bf16x8*)(qp + 32);

    const bf16* kbb = kbuf + (size_t)bh * 512 * 64;
    const bf16* vbb = vtb + (size_t)bh * 64 * 512;
    const unsigned char* idxp = idxg + ((size_t)b * 512 + rowbase + ((lane >> 4) << 2)) * 512;

    f32x4 o[4];
    float m_r[4], l_r[4];
#pragma unroll
    for (int i = 0; i < 4; i++) {
        o[i] = (f32x4){0.f, 0.f, 0.f, 0.f};
        m_r[i] = -1e30f;
        l_r[i] = 0.f;
    }

    const float L2E = 1.4426950408889634f;

    for (int s0 = 0; s0 < 512; s0 += 64) {
        f32x4 sa[4];
#pragma unroll
        for (int nf = 0; nf < 4; nf++) {
            sa[nf] = (f32x4){0.f, 0.f, 0.f, 0.f};
            const bf16* kp = kbb + (size_t)(s0 + nf * 16 + r) * 64 + ko;
            bf16x8 kf0 = *(const bf16x8*)kp;
            bf16x8 kf1 = *(const bf16x8*)(kp + 32);
            sa[nf] = MFMA(qf0, kf0, sa[nf]);
            sa[nf] = MFMA(qf1, kf1, sa[nf]);
        }
        // scale 1/sqrt(64) + RPE bias (sentinel 63 -> -1e30 masks padded cols)
#pragma unroll
        for (int nf = 0; nf < 4; nf++) {
            int scol = s0 + nf * 16 + r;
#pragma unroll
            for (int reg = 0; reg < 4; reg++) {
                float biasv = lut_s[idxp[reg * 512 + scol]];
                sa[nf][reg] = fmaf(sa[nf][reg], 0.125f, biasv);
            }
        }
        // online softmax, one row per (reg) per 16-lane group
#pragma unroll
        for (int reg = 0; reg < 4; reg++) {
            float mx = fmaxf(fmaxf(sa[0][reg], sa[1][reg]), fmaxf(sa[2][reg], sa[3][reg]));
            mx = fmaxf(mx, __shfl_xor(mx, 1));
            mx = fmaxf(mx, __shfl_xor(mx, 2));
            mx = fmaxf(mx, __shfl_xor(mx, 4));
            mx = fmaxf(mx, __shfl_xor(mx, 8));
            float mnew = fmaxf(m_r[reg], mx);
            float sc = exp2f((m_r[reg] - mnew) * L2E);
            m_r[reg] = mnew;
            float rs = 0.f;
#pragma unroll
            for (int nf = 0; nf < 4; nf++) {
                float p = exp2f((sa[nf][reg] - mnew) * L2E);
                sa[nf][reg] = p;
                rs += p;
            }
            rs += __shfl_xor(rs, 1);
            rs += __shfl_xor(rs, 2);
            rs += __shfl_xor(rs, 4);
            rs += __shfl_xor(rs, 8);
            l_r[reg] = l_r[reg] * sc + rs;
#pragma unroll
            for (int nf = 0; nf < 4; nf++) o[nf][reg] *= sc;
        }
        // P -> wave-private LDS slice (same-wave DS ops are in-order: no barrier)
#pragma unroll
        for (int nf = 0; nf < 4; nf++)
#pragma unroll
            for (int reg = 0; reg < 4; reg++)
                P[wave][((lane >> 4) << 2) + reg][nf * 16 + r] = (bf16)sa[nf][reg];
        bf16x8 pf0 = *(const bf16x8*)&P[wave][r][ko];
        bf16x8 pf1 = *(const bf16x8*)&P[wave][r][32 + ko];
#pragma unroll
        for (int nf = 0; nf < 4; nf++) {
            const bf16* vp = vbb + (size_t)(nf * 16 + r) * 512 + s0 + ko;
            bf16x8 vf0 = *(const bf16x8*)vp;
            bf16x8 vf1 = *(const bf16x8*)(vp + 32);
            o[nf] = MFMA(pf0, vf0, o[nf]);
            o[nf] = MFMA(pf1, vf1, o[nf]);
        }
    }
    // epilogue: normalize and store (t < 500 only)
#pragma unroll
    for (int reg = 0; reg < 4; reg++) {
        int t = rowbase + ((lane >> 4) << 2) + reg;
        if (t < 500) {
            float invl = 1.0f / l_r[reg];
            bf16* yp = yb + ((size_t)(b * 500 + t)) * 512 + h * 64;
#pragma unroll
            for (int nf = 0; nf < 4; nf++) yp[nf * 16 + r] = (bf16)(o[nf][reg] * invl);
        }
    }
}

// ---------------- output projection ----------------
// grid (4, 125): out[8000x512] f32 = Y[8000x512]bf16 * Wp_t[512x512]^T + b_proj.
__global__ __launch_bounds__(256) void proj_gemm(const bf16* __restrict__ Y,
                                                 const bf16* __restrict__ Wt,
                                                 const float* __restrict__ bp,
                                                 float* __restrict__ out) {
    const int lane = threadIdx.x & 63;
    const int wave = threadIdx.x >> 6;
    const int wr = wave >> 1, wc = wave & 1;
    const int m0 = blockIdx.y * 64 + wr * 32;
    const int n0 = blockIdx.x * 128 + wc * 64;
    const int r = lane & 15;
    const int ko = (lane >> 4) << 3;

    f32x4 acc[2][4];
#pragma unroll
    for (int i = 0; i < 2; i++)
#pragma unroll
        for (int j = 0; j < 4; j++) acc[i][j] = (f32x4){0.f, 0.f, 0.f, 0.f};

    gemm_core512(Y + (size_t)(m0 + r) * 512 + ko, Wt + (size_t)(n0 + r) * 512 + ko, acc);

#pragma unroll
    for (int mr = 0; mr < 2; mr++) {
#pragma unroll
        for (int nf = 0; nf < 4; nf++) {
            int n = n0 + nf * 16 + r;
            float bias = bp[n];
#pragma unroll
            for (int reg = 0; reg < 4; reg++) {
                int m = m0 + mr * 16 + ((lane >> 4) << 2) + reg;
                out[(size_t)m * 512 + n] = acc[mr][nf][reg] + bias;
            }
        }
    }
}

// ---------------- launch ----------------
extern "C" void kernel_launch(void* const* d_in, const int* in_sizes, int n_in,
                              void* d_out, int out_size, void* d_ws, size_t ws_size,
                              hipStream_t stream) {
    const float* x     = (const float*)d_in[0];
    const float* ct    = (const float*)d_in[1];
    const float* Wattn = (const float*)d_in[2];
    const float* battn = (const float*)d_in[3];
    const float* Wproj = (const float*)d_in[4];
    const float* bproj = (const float*)d_in[5];
    const float* lut   = (const float*)d_in[6];
    float* out = (float*)d_out;

    char* w = (char*)d_ws;
    bf16* xb   = (bf16*)w;                w += (size_t)8000 * 512 * 2;
    bf16* Wa_t = (bf16*)w;                w += (size_t)1536 * 512 * 2;
    bf16* Wp_t = (bf16*)w;                w += (size_t)512 * 512 * 2;
    bf16* qb   = (bf16*)w;                w += (size_t)16 * 8 * 512 * 64 * 2;
    bf16* kbuf = (bf16*)w;                w += (size_t)16 * 8 * 512 * 64 * 2;
    bf16* vtb  = (bf16*)w;                w += (size_t)16 * 8 * 64 * 512 * 2;
    unsigned char* idxb = (unsigned char*)w; w += (size_t)16 * 512 * 512;
    bf16* yb   = (bf16*)w;                w += (size_t)8000 * 512 * 2;

    cvt_f32_bf16<<<dim3(2048), 256, 0, stream>>>((const float4*)x, (ushort4*)xb, (8000 * 512) / 4);
    transpose_f32_bf16<<<dim3((512 * 1536 + 255) / 256), 256, 0, stream>>>(Wattn, Wa_t, 512, 1536);
    transpose_f32_bf16<<<dim3((512 * 512 + 255) / 256), 256, 0, stream>>>(Wproj, Wp_t, 512, 512);
    zero_f4<<<dim3(2048), 256, 0, stream>>>((float4*)qb, (3 * 8388608) / 16);
    bucket_kernel<<<dim3(16 * 512), 128, 0, stream>>>(ct, idxb);
    qkv_gemm<<<dim3(12, 125), 256, 0, stream>>>(xb, Wa_t, battn, qb, kbuf, vtb);
    attn_kernel<<<dim3(1024), 256, 0, stream>>>(qb, kbuf, vtb, idxb, lut, yb);
    proj_gemm<<<dim3(4, 125), 256, 0, stream>>>(yb, Wp_t, bproj, out);
}

// Round 3
// 163.264 us; speedup vs baseline: 1.2251x; 1.2251x over previous
//
#include <hip/hip_runtime.h>
#include <hip/hip_bf16.h>

typedef __bf16 bf16;
typedef __bf16 bf16x8 __attribute__((ext_vector_type(8)));
typedef float  f32x4  __attribute__((ext_vector_type(4)));

#define MFMA(a, b, c) __builtin_amdgcn_mfma_f32_16x16x32_bf16((a), (b), (c), 0, 0, 0)

// async global->LDS, 16B per lane. LDS dest = wave-uniform base + lane*16 (HW rule).
__device__ __forceinline__ void async_ld16(bf16* l, const bf16* g) {
    __builtin_amdgcn_global_load_lds(
        (const __attribute__((address_space(1))) void*)g,
        (__attribute__((address_space(3))) void*)l, 16, 0, 0);
}

// ---------------- prep kernels ----------------

__global__ void cvt_f32_bf16(const float4* __restrict__ src, ushort4* __restrict__ dst, int n4) {
    for (int i = blockIdx.x * blockDim.x + threadIdx.x; i < n4; i += gridDim.x * blockDim.x) {
        float4 v = src[i];
        ushort4 o;
        o.x = (unsigned short)(__bfloat16_as_ushort(__float2bfloat16(v.x)));
        o.y = (unsigned short)(__bfloat16_as_ushort(__float2bfloat16(v.y)));
        o.z = (unsigned short)(__bfloat16_as_ushort(__float2bfloat16(v.z)));
        o.w = (unsigned short)(__bfloat16_as_ushort(__float2bfloat16(v.w)));
        dst[i] = o;
    }
}

// src[K][N] f32 (row-major) -> dst[N][K] bf16
__global__ void transpose_f32_bf16(const float* __restrict__ src, bf16* __restrict__ dst,
                                   int K, int N) {
    int i = blockIdx.x * 256 + threadIdx.x;
    if (i < K * N) {
        int k = i / N, n = i % N;
        dst[n * K + k] = (bf16)src[i];
    }
}

__global__ void zero_f4(float4* __restrict__ p, int n4) {
    for (int i = blockIdx.x * blockDim.x + threadIdx.x; i < n4; i += gridDim.x * blockDim.x)
        p[i] = make_float4(0.f, 0.f, 0.f, 0.f);
}

// bucket ids: idx[b][t][s], padded 512x512, sentinel 63 (lut_s[63]=-1e30) for invalid.
__global__ void bucket_kernel(const float* __restrict__ ct, unsigned char* __restrict__ idx) {
    const int b = blockIdx.x >> 9;
    const int t = blockIdx.x & 511;
    const bool tv = (t < 500);
    float ctx = 0.f, cty = 0.f;
    if (tv) {
        ctx = ct[(b * 500 + t) * 2];
        cty = ct[(b * 500 + t) * 2 + 1];
    }
    const int s0 = threadIdx.x * 4;
    uchar4 o;
    unsigned char v[4];
#pragma unroll
    for (int j = 0; j < 4; j++) {
        int s = s0 + j;
        unsigned char r = 63;
        if (tv && s < 500) {
            float dx = ctx - ct[(b * 500 + s) * 2];
            float dy = cty - ct[(b * 500 + s) * 2 + 1];
            float dist = truncf(sqrtf(dx * dx + dy * dy) / 12.0f);
            int bi;
            if (dist <= 12.0f) {
                bi = (int)dist;
            } else {
                float lb = fminf(24.0f, rintf(12.0f + (logf(dist / 12.0f) * (1.0f / 2.0794415416798357f)) * 12.0f));
                bi = (int)lb;
            }
            r = (unsigned char)(bi + 24);
        }
        v[j] = r;
    }
    o.x = v[0]; o.y = v[1]; o.z = v[2]; o.w = v[3];
    *(uchar4*)(idx + ((size_t)blockIdx.x) * 512 + s0) = o;
}

// ---------------- LDS-staged 128-tile GEMM (m97 structure + T2 swizzle) ----------------
// C[BM=128 x BN] = A[M x 512] * Bt[N x 512]^T.  4 waves (WGM x WGN).
// LDS tiles [rows][BK=64] bf16, row stride 128B. Swizzle: byte ^= ((row&7)<<4),
// applied on the global SOURCE address (global_load_lds writes linearly, rule #21)
// and on the ds_read address (same involution).
// A/B-frag: row = 16*frag + (lane&15), k = kh*32 + (lane>>4)*8 (16B, ds_read_b128).
// D: col(n) = lane&15, row(m) = (lane>>4)*4 + reg.
// EPI 0: qkv scatter epilogue (bf16 q,k + transposed v). EPI 1: f32 out + bias.
template<int BN, int WGM, int WGN, int EPI>
__global__ __launch_bounds__(256) void gemm128(const bf16* __restrict__ A,
                                               const bf16* __restrict__ Bt,
                                               const float* __restrict__ bias,
                                               bf16* __restrict__ o_q,
                                               bf16* __restrict__ o_k,
                                               bf16* __restrict__ o_v,
                                               float* __restrict__ o_f) {
    constexpr int BM = 128, BK = 64, K = 512;
    constexpr int WM = BM / (WGM * 16);   // m-frags per wave
    constexpr int WN = BN / (WGN * 16);   // n-frags per wave

    __shared__ __align__(1024) bf16 lds[(BM + BN) * BK];
    bf16* ldsA = lds;
    bf16* ldsB = lds + BM * BK;

    const int lane = threadIdx.x & 63;
    const int wave = threadIdx.x >> 6;
    const int wr = wave / WGN;
    const int wc = wave % WGN;
    const int m0 = blockIdx.y * BM;
    const int n0 = blockIdx.x * BN;
    const int r = lane & 15;
    const int g = lane >> 4;

    f32x4 acc[WM][WN];
#pragma unroll
    for (int i = 0; i < WM; i++)
#pragma unroll
        for (int j = 0; j < WN; j++) acc[i][j] = (f32x4){0.f, 0.f, 0.f, 0.f};

    for (int kt = 0; kt < K; kt += BK) {
        // stage A: BM*8 16B-chunks, 256 threads
#pragma unroll
        for (int i = 0; i < BM * 8 / 256; i++) {
            int cbase = i * 256 + wave * 64;
            int c = cbase + lane;
            int row = c >> 3, cb = (c & 7) * 16;
            const bf16* src = A + (size_t)(m0 + row) * K + kt + ((cb ^ ((row & 7) << 4)) >> 1);
            async_ld16(ldsA + cbase * 8, src);
        }
        // stage B: BN*8 chunks
#pragma unroll
        for (int i = 0; i < BN * 8 / 256; i++) {
            int cbase = i * 256 + wave * 64;
            int c = cbase + lane;
            int row = c >> 3, cb = (c & 7) * 16;
            const bf16* src = Bt + (size_t)(n0 + row) * K + kt + ((cb ^ ((row & 7) << 4)) >> 1);
            async_ld16(ldsB + cbase * 8, src);
        }
        __syncthreads();  // compiler drains vmcnt before s_barrier
#pragma unroll
        for (int kh = 0; kh < 2; kh++) {
            bf16x8 af[WM], bfr[WN];
            const int cb = kh * 64 + g * 16;
#pragma unroll
            for (int mf = 0; mf < WM; mf++) {
                int fr = wr * WM * 16 + mf * 16 + r;
                af[mf] = *(const bf16x8*)&ldsA[fr * 64 + ((cb ^ ((fr & 7) << 4)) >> 1)];
            }
#pragma unroll
            for (int nf = 0; nf < WN; nf++) {
                int fr = wc * WN * 16 + nf * 16 + r;
                bfr[nf] = *(const bf16x8*)&ldsB[fr * 64 + ((cb ^ ((fr & 7) << 4)) >> 1)];
            }
#pragma unroll
            for (int mf = 0; mf < WM; mf++)
#pragma unroll
                for (int nf = 0; nf < WN; nf++)
                    acc[mf][nf] = MFMA(af[mf], bfr[nf], acc[mf][nf]);
        }
        __syncthreads();
    }

    // epilogue
#pragma unroll
    for (int mf = 0; mf < WM; mf++) {
#pragma unroll
        for (int nf = 0; nf < WN; nf++) {
            int n = n0 + wc * WN * 16 + nf * 16 + r;
            float bv = bias[n];
#pragma unroll
            for (int reg = 0; reg < 4; reg++) {
                int m = m0 + wr * WM * 16 + mf * 16 + g * 4 + reg;
                if (m < 8000) {
                    float v = acc[mf][nf][reg] + bv;
                    if (EPI == 0) {
                        int b = m / 500, t = m - b * 500;
                        if (n < 512) {
                            int h = n >> 6, d = n & 63;
                            o_q[(((size_t)(b * 8 + h)) * 512 + t) * 64 + d] = (bf16)v;
                        } else if (n < 1024) {
                            int n2 = n - 512;
                            int h = n2 >> 6, d = n2 & 63;
                            o_k[(((size_t)(b * 8 + h)) * 512 + t) * 64 + d] = (bf16)v;
                        } else {
                            int n2 = n - 1024;
                            int h = n2 >> 6, d = n2 & 63;
                            o_v[(((size_t)(b * 8 + h)) * 64 + d) * 512 + t] = (bf16)v;
                        }
                    } else {
                        o_f[(size_t)m * 512 + n] = v;
                    }
                }
            }
        }
    }
}

// ---------------- fused attention (unchanged this round) ----------------
__global__ __launch_bounds__(256) void attn_kernel(const bf16* __restrict__ qb,
                                                   const bf16* __restrict__ kbuf,
                                                   const bf16* __restrict__ vtb,
                                                   const unsigned char* __restrict__ idxg,
                                                   const float* __restrict__ lut,
                                                   bf16* __restrict__ yb) {
    const int lane = threadIdx.x & 63;
    const int wave = threadIdx.x >> 6;
    const int bh = blockIdx.x >> 3;
    const int qt = blockIdx.x & 7;
    const int b = bh >> 3;
    const int h = bh & 7;

    __shared__ float lut_s[64];
    __shared__ __align__(16) bf16 P[4][16][72];
    if (threadIdx.x < 64)
        lut_s[threadIdx.x] = (threadIdx.x < 49) ? lut[h * 49 + threadIdx.x] : -1e30f;
    __syncthreads();

    const int r = lane & 15;
    const int ko = (lane >> 4) << 3;
    const int rowbase = qt * 64 + wave * 16;

    const bf16* qp = qb + ((size_t)bh * 512 + rowbase + r) * 64 + ko;
    bf16x8 qf0 = *(const bf16x8*)qp;
    bf16x8 qf1 = *(const bf16x8*)(qp + 32);

    const bf16* kbb = kbuf + (size_t)bh * 512 * 64;
    const bf16* vbb = vtb + (size_t)bh * 64 * 512;
    const unsigned char* idxp = idxg + ((size_t)b * 512 + rowbase + ((lane >> 4) << 2)) * 512;

    f32x4 o[4];
    float m_r[4], l_r[4];
#pragma unroll
    for (int i = 0; i < 4; i++) {
        o[i] = (f32x4){0.f, 0.f, 0.f, 0.f};
        m_r[i] = -1e30f;
        l_r[i] = 0.f;
    }

    const float L2E = 1.4426950408889634f;

    for (int s0 = 0; s0 < 512; s0 += 64) {
        f32x4 sa[4];
#pragma unroll
        for (int nf = 0; nf < 4; nf++) {
            sa[nf] = (f32x4){0.f, 0.f, 0.f, 0.f};
            const bf16* kp = kbb + (size_t)(s0 + nf * 16 + r) * 64 + ko;
            bf16x8 kf0 = *(const bf16x8*)kp;
            bf16x8 kf1 = *(const bf16x8*)(kp + 32);
            sa[nf] = MFMA(qf0, kf0, sa[nf]);
            sa[nf] = MFMA(qf1, kf1, sa[nf]);
        }
#pragma unroll
        for (int nf = 0; nf < 4; nf++) {
            int scol = s0 + nf * 16 + r;
#pragma unroll
            for (int reg = 0; reg < 4; reg++) {
                float biasv = lut_s[idxp[reg * 512 + scol]];
                sa[nf][reg] = fmaf(sa[nf][reg], 0.125f, biasv);
            }
        }
#pragma unroll
        for (int reg = 0; reg < 4; reg++) {
            float mx = fmaxf(fmaxf(sa[0][reg], sa[1][reg]), fmaxf(sa[2][reg], sa[3][reg]));
            mx = fmaxf(mx, __shfl_xor(mx, 1));
            mx = fmaxf(mx, __shfl_xor(mx, 2));
            mx = fmaxf(mx, __shfl_xor(mx, 4));
            mx = fmaxf(mx, __shfl_xor(mx, 8));
            float mnew = fmaxf(m_r[reg], mx);
            float sc = exp2f((m_r[reg] - mnew) * L2E);
            m_r[reg] = mnew;
            float rs = 0.f;
#pragma unroll
            for (int nf = 0; nf < 4; nf++) {
                float p = exp2f((sa[nf][reg] - mnew) * L2E);
                sa[nf][reg] = p;
                rs += p;
            }
            rs += __shfl_xor(rs, 1);
            rs += __shfl_xor(rs, 2);
            rs += __shfl_xor(rs, 4);
            rs += __shfl_xor(rs, 8);
            l_r[reg] = l_r[reg] * sc + rs;
#pragma unroll
            for (int nf = 0; nf < 4; nf++) o[nf][reg] *= sc;
        }
#pragma unroll
        for (int nf = 0; nf < 4; nf++)
#pragma unroll
            for (int reg = 0; reg < 4; reg++)
                P[wave][((lane >> 4) << 2) + reg][nf * 16 + r] = (bf16)sa[nf][reg];
        bf16x8 pf0 = *(const bf16x8*)&P[wave][r][ko];
        bf16x8 pf1 = *(const bf16x8*)&P[wave][r][32 + ko];
#pragma unroll
        for (int nf = 0; nf < 4; nf++) {
            const bf16* vp = vbb + (size_t)(nf * 16 + r) * 512 + s0 + ko;
            bf16x8 vf0 = *(const bf16x8*)vp;
            bf16x8 vf1 = *(const bf16x8*)(vp + 32);
            o[nf] = MFMA(pf0, vf0, o[nf]);
            o[nf] = MFMA(pf1, vf1, o[nf]);
        }
    }
#pragma unroll
    for (int reg = 0; reg < 4; reg++) {
        int t = rowbase + ((lane >> 4) << 2) + reg;
        if (t < 500) {
            float invl = 1.0f / l_r[reg];
            bf16* yp = yb + ((size_t)(b * 500 + t)) * 512 + h * 64;
#pragma unroll
            for (int nf = 0; nf < 4; nf++) yp[nf * 16 + r] = (bf16)(o[nf][reg] * invl);
        }
    }
}

// ---------------- launch ----------------
extern "C" void kernel_launch(void* const* d_in, const int* in_sizes, int n_in,
                              void* d_out, int out_size, void* d_ws, size_t ws_size,
                              hipStream_t stream) {
    const float* x     = (const float*)d_in[0];
    const float* ct    = (const float*)d_in[1];
    const float* Wattn = (const float*)d_in[2];
    const float* battn = (const float*)d_in[3];
    const float* Wproj = (const float*)d_in[4];
    const float* bproj = (const float*)d_in[5];
    const float* lut   = (const float*)d_in[6];
    float* out = (float*)d_out;

    char* w = (char*)d_ws;
    bf16* xb   = (bf16*)w;                w += (size_t)8064 * 512 * 2;  // padded to 63*128 rows
    bf16* Wa_t = (bf16*)w;                w += (size_t)1536 * 512 * 2;
    bf16* Wp_t = (bf16*)w;                w += (size_t)512 * 512 * 2;
    bf16* qb   = (bf16*)w;                w += (size_t)16 * 8 * 512 * 64 * 2;
    bf16* kbuf = (bf16*)w;                w += (size_t)16 * 8 * 512 * 64 * 2;
    bf16* vtb  = (bf16*)w;                w += (size_t)16 * 8 * 64 * 512 * 2;
    unsigned char* idxb = (unsigned char*)w; w += (size_t)16 * 512 * 512;
    bf16* yb   = (bf16*)w;                w += (size_t)8064 * 512 * 2;  // padded

    cvt_f32_bf16<<<dim3(2048), 256, 0, stream>>>((const float4*)x, (ushort4*)xb, (8000 * 512) / 4);
    transpose_f32_bf16<<<dim3((512 * 1536 + 255) / 256), 256, 0, stream>>>(Wattn, Wa_t, 512, 1536);
    transpose_f32_bf16<<<dim3((512 * 512 + 255) / 256), 256, 0, stream>>>(Wproj, Wp_t, 512, 512);
    // zero q/k/vtb (t-padding) + xb tail rows + yb tail rows
    zero_f4<<<dim3(2048), 256, 0, stream>>>((float4*)qb, (3 * 8388608) / 16);
    zero_f4<<<dim3(16), 256, 0, stream>>>((float4*)(xb + (size_t)8000 * 512), 64 * 512 * 2 / 16);
    zero_f4<<<dim3(16), 256, 0, stream>>>((float4*)(yb + (size_t)8000 * 512), 64 * 512 * 2 / 16);
    bucket_kernel<<<dim3(16 * 512), 128, 0, stream>>>(ct, idxb);

    // QKV: M=8064(63x128), N=1536(12x128); waves 2x2, each 64x64
    gemm128<128, 2, 2, 0><<<dim3(12, 63), 256, 0, stream>>>(xb, Wa_t, battn, qb, kbuf, vtb, nullptr);

    attn_kernel<<<dim3(1024), 256, 0, stream>>>(qb, kbuf, vtb, idxb, lut, yb);

    // proj: N=512(8x64); waves 4x1, each 32x64
    gemm128<64, 4, 1, 1><<<dim3(8, 63), 256, 0, stream>>>(yb, Wp_t, bproj, nullptr, nullptr, nullptr, out);
}

// Round 4
// 151.947 us; speedup vs baseline: 1.3163x; 1.0745x over previous
//
#include <hip/hip_runtime.h>
#include <hip/hip_bf16.h>

typedef __bf16 bf16;
typedef __bf16 bf16x8 __attribute__((ext_vector_type(8)));
typedef float  f32x4  __attribute__((ext_vector_type(4)));

#define MFMA(a, b, c) __builtin_amdgcn_mfma_f32_16x16x32_bf16((a), (b), (c), 0, 0, 0)

__device__ __forceinline__ void async_ld16(bf16* l, const bf16* g) {
    __builtin_amdgcn_global_load_lds(
        (const __attribute__((address_space(1))) void*)g,
        (__attribute__((address_space(3))) void*)l, 16, 0, 0);
}

// ---------------- prep kernels ----------------

__global__ void cvt_f32_bf16(const float4* __restrict__ src, ushort4* __restrict__ dst, int n4) {
    for (int i = blockIdx.x * blockDim.x + threadIdx.x; i < n4; i += gridDim.x * blockDim.x) {
        float4 v = src[i];
        ushort4 o;
        o.x = (unsigned short)(__bfloat16_as_ushort(__float2bfloat16(v.x)));
        o.y = (unsigned short)(__bfloat16_as_ushort(__float2bfloat16(v.y)));
        o.z = (unsigned short)(__bfloat16_as_ushort(__float2bfloat16(v.z)));
        o.w = (unsigned short)(__bfloat16_as_ushort(__float2bfloat16(v.w)));
        dst[i] = o;
    }
}

__global__ void transpose_f32_bf16(const float* __restrict__ src, bf16* __restrict__ dst,
                                   int K, int N) {
    int i = blockIdx.x * 256 + threadIdx.x;
    if (i < K * N) {
        int k = i / N, n = i % N;
        dst[n * K + k] = (bf16)src[i];
    }
}

__global__ void zero_f4(float4* __restrict__ p, int n4) {
    for (int i = blockIdx.x * blockDim.x + threadIdx.x; i < n4; i += gridDim.x * blockDim.x)
        p[i] = make_float4(0.f, 0.f, 0.f, 0.f);
}

__global__ void bucket_kernel(const float* __restrict__ ct, unsigned char* __restrict__ idx) {
    const int b = blockIdx.x >> 9;
    const int t = blockIdx.x & 511;
    const bool tv = (t < 500);
    float ctx = 0.f, cty = 0.f;
    if (tv) {
        ctx = ct[(b * 500 + t) * 2];
        cty = ct[(b * 500 + t) * 2 + 1];
    }
    const int s0 = threadIdx.x * 4;
    uchar4 o;
    unsigned char v[4];
#pragma unroll
    for (int j = 0; j < 4; j++) {
        int s = s0 + j;
        unsigned char r = 63;
        if (tv && s < 500) {
            float dx = ctx - ct[(b * 500 + s) * 2];
            float dy = cty - ct[(b * 500 + s) * 2 + 1];
            float dist = truncf(sqrtf(dx * dx + dy * dy) / 12.0f);
            int bi;
            if (dist <= 12.0f) {
                bi = (int)dist;
            } else {
                float lb = fminf(24.0f, rintf(12.0f + (logf(dist / 12.0f) * (1.0f / 2.0794415416798357f)) * 12.0f));
                bi = (int)lb;
            }
            r = (unsigned char)(bi + 24);
        }
        v[j] = r;
    }
    o.x = v[0]; o.y = v[1]; o.z = v[2]; o.w = v[3];
    *(uchar4*)(idx + ((size_t)blockIdx.x) * 512 + s0) = o;
}

// ---------------- double-buffered pipelined 128-tile GEMM (T2+T3+T4+T1) ----------------
// C[128 x BN] = A[M x 512] * Bt[N x 512]^T. 4 waves (WGM x WGN).
// LDS [rows][BK=64] bf16, st-swizzle byte ^= ((row&7)<<4) applied on the global
// SOURCE (global_load_lds writes linearly) and on ds_read (same involution).
// 2-phase pipeline: stage(t+1) issued BEFORE compute(t); s_waitcnt vmcnt(NA+NB)
// (never 0 mid-loop) so next tile's loads stay in flight across the barrier.
template<int BN, int WGM, int WGN, int EPI>
__global__ __launch_bounds__(256) void gemm128(const bf16* __restrict__ A,
                                               const bf16* __restrict__ Bt,
                                               const float* __restrict__ bias,
                                               bf16* __restrict__ o_q,
                                               bf16* __restrict__ o_k,
                                               bf16* __restrict__ o_v,
                                               float* __restrict__ o_f) {
    constexpr int BM = 128, BK = 64, K = 512, NT = K / BK;
    constexpr int WM = BM / (WGM * 16);
    constexpr int WN = BN / (WGN * 16);
    constexpr int NA = BM * 8 / 256;   // stage instrs per thread (A)
    constexpr int NB = BN * 8 / 256;   // stage instrs per thread (B)
    constexpr int LD = (BM + BN) * BK; // elems per buffer

    __shared__ __align__(1024) bf16 lds[2 * LD];

    const int lane = threadIdx.x & 63;
    const int wave = threadIdx.x >> 6;

    // T1: bijective XCD-chunked blockIdx remap (m204 form; nwg may not be %8)
    const int gdx = gridDim.x;
    const int nwg = gdx * gridDim.y;
    const int bid = blockIdx.y * gdx + blockIdx.x;
    const int qq = nwg >> 3, rr = nwg & 7;
    const int xcd = bid & 7, jj = bid >> 3;
    const int wg = (xcd < rr ? xcd * (qq + 1) : rr * (qq + 1) + (xcd - rr) * qq) + jj;
    const int m0 = (wg / gdx) * BM;
    const int n0 = (wg % gdx) * BN;

    const int wr = wave / WGN, wc = wave % WGN;
    const int r = lane & 15, g = lane >> 4;

    // per-thread staging addresses (kt-invariant)
    const bf16* pa[NA];
    const bf16* pb[NB];
    int loA[NA], loB[NB];
#pragma unroll
    for (int i = 0; i < NA; i++) {
        int cbase = i * 256 + wave * 64;
        int c = cbase + lane;
        int row = c >> 3, cb = (c & 7) * 16;
        pa[i] = A + (size_t)(m0 + row) * K + ((cb ^ ((row & 7) << 4)) >> 1);
        loA[i] = cbase * 8;
    }
#pragma unroll
    for (int i = 0; i < NB; i++) {
        int cbase = i * 256 + wave * 64;
        int c = cbase + lane;
        int row = c >> 3, cb = (c & 7) * 16;
        pb[i] = Bt + (size_t)(n0 + row) * K + ((cb ^ ((row & 7) << 4)) >> 1);
        loB[i] = cbase * 8;
    }

    f32x4 acc[WM][WN];
#pragma unroll
    for (int i = 0; i < WM; i++)
#pragma unroll
        for (int j = 0; j < WN; j++) acc[i][j] = (f32x4){0.f, 0.f, 0.f, 0.f};

    auto stage = [&](int buf, int kt) {
        bf16* la = lds + buf * LD;
        bf16* lb = la + BM * BK;
#pragma unroll
        for (int i = 0; i < NA; i++) async_ld16(la + loA[i], pa[i] + kt);
#pragma unroll
        for (int i = 0; i < NB; i++) async_ld16(lb + loB[i], pb[i] + kt);
    };

    stage(0, 0);
    int cur = 0;
#pragma unroll
    for (int t = 0; t < NT; t++) {
        if (t + 1 < NT) {
            stage(cur ^ 1, (t + 1) * BK);
            asm volatile("s_waitcnt vmcnt(%0)" ::"i"(NA + NB) : "memory");
        } else {
            asm volatile("s_waitcnt vmcnt(0)" ::: "memory");
        }
        __builtin_amdgcn_s_barrier();
        const bf16* la = lds + cur * LD;
        const bf16* lb = la + BM * BK;
#pragma unroll
        for (int kh = 0; kh < 2; kh++) {
            const int cb = kh * 64 + g * 16;
            bf16x8 af[WM], bfv[WN];
#pragma unroll
            for (int mf = 0; mf < WM; mf++) {
                int fr = wr * WM * 16 + mf * 16 + r;
                af[mf] = *(const bf16x8*)&la[fr * 64 + ((cb ^ ((fr & 7) << 4)) >> 1)];
            }
#pragma unroll
            for (int nf = 0; nf < WN; nf++) {
                int fr = wc * WN * 16 + nf * 16 + r;
                bfv[nf] = *(const bf16x8*)&lb[fr * 64 + ((cb ^ ((fr & 7) << 4)) >> 1)];
            }
#pragma unroll
            for (int mf = 0; mf < WM; mf++)
#pragma unroll
                for (int nf = 0; nf < WN; nf++)
                    acc[mf][nf] = MFMA(af[mf], bfv[nf], acc[mf][nf]);
        }
        asm volatile("" ::: "memory");
        __builtin_amdgcn_s_barrier();
        cur ^= 1;
    }

    // epilogue
#pragma unroll
    for (int mf = 0; mf < WM; mf++) {
#pragma unroll
        for (int nf = 0; nf < WN; nf++) {
            int n = n0 + wc * WN * 16 + nf * 16 + r;
            float bv = bias[n];
#pragma unroll
            for (int reg = 0; reg < 4; reg++) {
                int m = m0 + wr * WM * 16 + mf * 16 + g * 4 + reg;
                if (m < 8000) {
                    float v = acc[mf][nf][reg] + bv;
                    if (EPI == 0) {
                        int b = m / 500, t = m - b * 500;
                        if (n < 512) {
                            int h = n >> 6, d = n & 63;
                            o_q[(((size_t)(b * 8 + h)) * 512 + t) * 64 + d] = (bf16)v;
                        } else if (n < 1024) {
                            int n2 = n - 512;
                            int h = n2 >> 6, d = n2 & 63;
                            o_k[(((size_t)(b * 8 + h)) * 512 + t) * 64 + d] = (bf16)v;
                        } else {
                            int n2 = n - 1024;
                            int h = n2 >> 6, d = n2 & 63;
                            o_v[(((size_t)(b * 8 + h)) * 64 + d) * 512 + t] = (bf16)v;
                        }
                    } else {
                        o_f[(size_t)m * 512 + n] = v;
                    }
                }
            }
        }
    }
}

// ---------------- fused attention (unchanged this round) ----------------
__global__ __launch_bounds__(256) void attn_kernel(const bf16* __restrict__ qb,
                                                   const bf16* __restrict__ kbuf,
                                                   const bf16* __restrict__ vtb,
                                                   const unsigned char* __restrict__ idxg,
                                                   const float* __restrict__ lut,
                                                   bf16* __restrict__ yb) {
    const int lane = threadIdx.x & 63;
    const int wave = threadIdx.x >> 6;
    const int bh = blockIdx.x >> 3;
    const int qt = blockIdx.x & 7;
    const int b = bh >> 3;
    const int h = bh & 7;

    __shared__ float lut_s[64];
    __shared__ __align__(16) bf16 P[4][16][72];
    if (threadIdx.x < 64)
        lut_s[threadIdx.x] = (threadIdx.x < 49) ? lut[h * 49 + threadIdx.x] : -1e30f;
    __syncthreads();

    const int r = lane & 15;
    const int ko = (lane >> 4) << 3;
    const int rowbase = qt * 64 + wave * 16;

    const bf16* qp = qb + ((size_t)bh * 512 + rowbase + r) * 64 + ko;
    bf16x8 qf0 = *(const bf16x8*)qp;
    bf16x8 qf1 = *(const bf16x8*)(qp + 32);

    const bf16* kbb = kbuf + (size_t)bh * 512 * 64;
    const bf16* vbb = vtb + (size_t)bh * 64 * 512;
    const unsigned char* idxp = idxg + ((size_t)b * 512 + rowbase + ((lane >> 4) << 2)) * 512;

    f32x4 o[4];
    float m_r[4], l_r[4];
#pragma unroll
    for (int i = 0; i < 4; i++) {
        o[i] = (f32x4){0.f, 0.f, 0.f, 0.f};
        m_r[i] = -1e30f;
        l_r[i] = 0.f;
    }

    const float L2E = 1.4426950408889634f;

    for (int s0 = 0; s0 < 512; s0 += 64) {
        f32x4 sa[4];
#pragma unroll
        for (int nf = 0; nf < 4; nf++) {
            sa[nf] = (f32x4){0.f, 0.f, 0.f, 0.f};
            const bf16* kp = kbb + (size_t)(s0 + nf * 16 + r) * 64 + ko;
            bf16x8 kf0 = *(const bf16x8*)kp;
            bf16x8 kf1 = *(const bf16x8*)(kp + 32);
            sa[nf] = MFMA(qf0, kf0, sa[nf]);
            sa[nf] = MFMA(qf1, kf1, sa[nf]);
        }
#pragma unroll
        for (int nf = 0; nf < 4; nf++) {
            int scol = s0 + nf * 16 + r;
#pragma unroll
            for (int reg = 0; reg < 4; reg++) {
                float biasv = lut_s[idxp[reg * 512 + scol]];
                sa[nf][reg] = fmaf(sa[nf][reg], 0.125f, biasv);
            }
        }
#pragma unroll
        for (int reg = 0; reg < 4; reg++) {
            float mx = fmaxf(fmaxf(sa[0][reg], sa[1][reg]), fmaxf(sa[2][reg], sa[3][reg]));
            mx = fmaxf(mx, __shfl_xor(mx, 1));
            mx = fmaxf(mx, __shfl_xor(mx, 2));
            mx = fmaxf(mx, __shfl_xor(mx, 4));
            mx = fmaxf(mx, __shfl_xor(mx, 8));
            float mnew = fmaxf(m_r[reg], mx);
            float sc = exp2f((m_r[reg] - mnew) * L2E);
            m_r[reg] = mnew;
            float rs = 0.f;
#pragma unroll
            for (int nf = 0; nf < 4; nf++) {
                float p = exp2f((sa[nf][reg] - mnew) * L2E);
                sa[nf][reg] = p;
                rs += p;
            }
            rs += __shfl_xor(rs, 1);
            rs += __shfl_xor(rs, 2);
            rs += __shfl_xor(rs, 4);
            rs += __shfl_xor(rs, 8);
            l_r[reg] = l_r[reg] * sc + rs;
#pragma unroll
            for (int nf = 0; nf < 4; nf++) o[nf][reg] *= sc;
        }
#pragma unroll
        for (int nf = 0; nf < 4; nf++)
#pragma unroll
            for (int reg = 0; reg < 4; reg++)
                P[wave][((lane >> 4) << 2) + reg][nf * 16 + r] = (bf16)sa[nf][reg];
        bf16x8 pf0 = *(const bf16x8*)&P[wave][r][ko];
        bf16x8 pf1 = *(const bf16x8*)&P[wave][r][32 + ko];
#pragma unroll
        for (int nf = 0; nf < 4; nf++) {
            const bf16* vp = vbb + (size_t)(nf * 16 + r) * 512 + s0 + ko;
            bf16x8 vf0 = *(const bf16x8*)vp;
            bf16x8 vf1 = *(const bf16x8*)(vp + 32);
            o[nf] = MFMA(pf0, vf0, o[nf]);
            o[nf] = MFMA(pf1, vf1, o[nf]);
        }
    }
#pragma unroll
    for (int reg = 0; reg < 4; reg++) {
        int t = rowbase + ((lane >> 4) << 2) + reg;
        if (t < 500) {
            float invl = 1.0f / l_r[reg];
            bf16* yp = yb + ((size_t)(b * 500 + t)) * 512 + h * 64;
#pragma unroll
            for (int nf = 0; nf < 4; nf++) yp[nf * 16 + r] = (bf16)(o[nf][reg] * invl);
        }
    }
}

// ---------------- launch ----------------
extern "C" void kernel_launch(void* const* d_in, const int* in_sizes, int n_in,
                              void* d_out, int out_size, void* d_ws, size_t ws_size,
                              hipStream_t stream) {
    const float* x     = (const float*)d_in[0];
    const float* ct    = (const float*)d_in[1];
    const float* Wattn = (const float*)d_in[2];
    const float* battn = (const float*)d_in[3];
    const float* Wproj = (const float*)d_in[4];
    const float* bproj = (const float*)d_in[5];
    const float* lut   = (const float*)d_in[6];
    float* out = (float*)d_out;

    char* w = (char*)d_ws;
    bf16* xb   = (bf16*)w;                w += (size_t)8064 * 512 * 2;
    bf16* Wa_t = (bf16*)w;                w += (size_t)1536 * 512 * 2;
    bf16* Wp_t = (bf16*)w;                w += (size_t)512 * 512 * 2;
    bf16* qb   = (bf16*)w;                w += (size_t)16 * 8 * 512 * 64 * 2;
    bf16* kbuf = (bf16*)w;                w += (size_t)16 * 8 * 512 * 64 * 2;
    bf16* vtb  = (bf16*)w;                w += (size_t)16 * 8 * 64 * 512 * 2;
    unsigned char* idxb = (unsigned char*)w; w += (size_t)16 * 512 * 512;
    bf16* yb   = (bf16*)w;                w += (size_t)8064 * 512 * 2;

    cvt_f32_bf16<<<dim3(2048), 256, 0, stream>>>((const float4*)x, (ushort4*)xb, (8000 * 512) / 4);
    transpose_f32_bf16<<<dim3((512 * 1536 + 255) / 256), 256, 0, stream>>>(Wattn, Wa_t, 512, 1536);
    transpose_f32_bf16<<<dim3((512 * 512 + 255) / 256), 256, 0, stream>>>(Wproj, Wp_t, 512, 512);
    zero_f4<<<dim3(2048), 256, 0, stream>>>((float4*)qb, (3 * 8388608) / 16);
    zero_f4<<<dim3(16), 256, 0, stream>>>((float4*)(xb + (size_t)8000 * 512), 64 * 512 * 2 / 16);
    zero_f4<<<dim3(16), 256, 0, stream>>>((float4*)(yb + (size_t)8000 * 512), 64 * 512 * 2 / 16);
    bucket_kernel<<<dim3(16 * 512), 128, 0, stream>>>(ct, idxb);

    // QKV: M=8064(63x128), N=1536(12x128); waves 2x2, each 64x64
    gemm128<128, 2, 2, 0><<<dim3(12, 63), 256, 0, stream>>>(xb, Wa_t, battn, qb, kbuf, vtb, nullptr);

    attn_kernel<<<dim3(1024), 256, 0, stream>>>(qb, kbuf, vtb, idxb, lut, yb);

    // proj: N=512(8x64); waves 4x1, each 32x64
    gemm128<64, 4, 1, 1><<<dim3(8, 63), 256, 0, stream>>>(yb, Wp_t, bproj, nullptr, nullptr, nullptr, out);
}

// Round 5
// 133.801 us; speedup vs baseline: 1.4948x; 1.1356x over previous
//
#include <hip/hip_runtime.h>
#include <hip/hip_bf16.h>

typedef __bf16 bf16;
typedef __bf16 bf16x4 __attribute__((ext_vector_type(4)));
typedef __bf16 bf16x8 __attribute__((ext_vector_type(8)));
typedef float  f32x4  __attribute__((ext_vector_type(4)));

#define MFMA(a, b, c) __builtin_amdgcn_mfma_f32_16x16x32_bf16((a), (b), (c), 0, 0, 0)

__device__ __forceinline__ void async_ld16(bf16* l, const bf16* g) {
    __builtin_amdgcn_global_load_lds(
        (const __attribute__((address_space(1))) void*)g,
        (__attribute__((address_space(3))) void*)l, 16, 0, 0);
}

// ---------------- prep kernels ----------------

__global__ void cvt_f32_bf16(const float4* __restrict__ src, ushort4* __restrict__ dst, int n4) {
    for (int i = blockIdx.x * blockDim.x + threadIdx.x; i < n4; i += gridDim.x * blockDim.x) {
        float4 v = src[i];
        ushort4 o;
        o.x = (unsigned short)(__bfloat16_as_ushort(__float2bfloat16(v.x)));
        o.y = (unsigned short)(__bfloat16_as_ushort(__float2bfloat16(v.y)));
        o.z = (unsigned short)(__bfloat16_as_ushort(__float2bfloat16(v.z)));
        o.w = (unsigned short)(__bfloat16_as_ushort(__float2bfloat16(v.w)));
        dst[i] = o;
    }
}

__global__ void transpose_f32_bf16(const float* __restrict__ src, bf16* __restrict__ dst,
                                   int K, int N) {
    int i = blockIdx.x * 256 + threadIdx.x;
    if (i < K * N) {
        int k = i / N, n = i % N;
        dst[n * K + k] = (bf16)src[i];
    }
}

__global__ void zero_f4(float4* __restrict__ p, int n4) {
    for (int i = blockIdx.x * blockDim.x + threadIdx.x; i < n4; i += gridDim.x * blockDim.x)
        p[i] = make_float4(0.f, 0.f, 0.f, 0.f);
}

__global__ void bucket_kernel(const float* __restrict__ ct, unsigned char* __restrict__ idx) {
    const int b = blockIdx.x >> 9;
    const int t = blockIdx.x & 511;
    const bool tv = (t < 500);
    float ctx = 0.f, cty = 0.f;
    if (tv) {
        ctx = ct[(b * 500 + t) * 2];
        cty = ct[(b * 500 + t) * 2 + 1];
    }
    const int s0 = threadIdx.x * 4;
    uchar4 o;
    unsigned char v[4];
#pragma unroll
    for (int j = 0; j < 4; j++) {
        int s = s0 + j;
        unsigned char r = 63;
        if (tv && s < 500) {
            float dx = ctx - ct[(b * 500 + s) * 2];
            float dy = cty - ct[(b * 500 + s) * 2 + 1];
            float dist = truncf(sqrtf(dx * dx + dy * dy) / 12.0f);
            int bi;
            if (dist <= 12.0f) {
                bi = (int)dist;
            } else {
                float lb = fminf(24.0f, rintf(12.0f + (logf(dist / 12.0f) * (1.0f / 2.0794415416798357f)) * 12.0f));
                bi = (int)lb;
            }
            r = (unsigned char)(bi + 24);
        }
        v[j] = r;
    }
    o.x = v[0]; o.y = v[1]; o.z = v[2]; o.w = v[3];
    *(uchar4*)(idx + ((size_t)blockIdx.x) * 512 + s0) = o;
}

// ---------------- double-buffered pipelined 128-tile GEMM ----------------
// Core unchanged from R4. EPI 0: NEW coalesced epilogue — assemble 128x128 bf16
// tile in LDS (XOR-swizzled), then 16B/lane coalesced stores. v-blocks store the
// tile n-major so the read-back is contiguous along t (the transposed output dim).
template<int BN, int WGM, int WGN, int EPI>
__global__ __launch_bounds__(256) void gemm128(const bf16* __restrict__ A,
                                               const bf16* __restrict__ Bt,
                                               const float* __restrict__ bias,
                                               bf16* __restrict__ o_q,
                                               bf16* __restrict__ o_k,
                                               bf16* __restrict__ o_v,
                                               float* __restrict__ o_f) {
    constexpr int BM = 128, BK = 64, K = 512, NT = K / BK;
    constexpr int WM = BM / (WGM * 16);
    constexpr int WN = BN / (WGN * 16);
    constexpr int NA = BM * 8 / 256;
    constexpr int NB = BN * 8 / 256;
    constexpr int LD = (BM + BN) * BK;

    __shared__ __align__(1024) bf16 lds[2 * LD];

    const int lane = threadIdx.x & 63;
    const int wave = threadIdx.x >> 6;

    // T1 bijective XCD-chunked remap
    const int gdx = gridDim.x;
    const int nwg = gdx * gridDim.y;
    const int bid = blockIdx.y * gdx + blockIdx.x;
    const int qq = nwg >> 3, rr = nwg & 7;
    const int xcd = bid & 7, jj = bid >> 3;
    const int wg = (xcd < rr ? xcd * (qq + 1) : rr * (qq + 1) + (xcd - rr) * qq) + jj;
    const int m0 = (wg / gdx) * BM;
    const int n0 = (wg % gdx) * BN;

    const int wr = wave / WGN, wc = wave % WGN;
    const int r = lane & 15, g = lane >> 4;

    const bf16* pa[NA];
    const bf16* pb[NB];
    int loA[NA], loB[NB];
#pragma unroll
    for (int i = 0; i < NA; i++) {
        int cbase = i * 256 + wave * 64;
        int c = cbase + lane;
        int row = c >> 3, cb = (c & 7) * 16;
        pa[i] = A + (size_t)(m0 + row) * K + ((cb ^ ((row & 7) << 4)) >> 1);
        loA[i] = cbase * 8;
    }
#pragma unroll
    for (int i = 0; i < NB; i++) {
        int cbase = i * 256 + wave * 64;
        int c = cbase + lane;
        int row = c >> 3, cb = (c & 7) * 16;
        pb[i] = Bt + (size_t)(n0 + row) * K + ((cb ^ ((row & 7) << 4)) >> 1);
        loB[i] = cbase * 8;
    }

    f32x4 acc[WM][WN];
#pragma unroll
    for (int i = 0; i < WM; i++)
#pragma unroll
        for (int j = 0; j < WN; j++) acc[i][j] = (f32x4){0.f, 0.f, 0.f, 0.f};

    auto stage = [&](int buf, int kt) {
        bf16* la = lds + buf * LD;
        bf16* lb = la + BM * BK;
#pragma unroll
        for (int i = 0; i < NA; i++) async_ld16(la + loA[i], pa[i] + kt);
#pragma unroll
        for (int i = 0; i < NB; i++) async_ld16(lb + loB[i], pb[i] + kt);
    };

    stage(0, 0);
    int cur = 0;
#pragma unroll
    for (int t = 0; t < NT; t++) {
        if (t + 1 < NT) {
            stage(cur ^ 1, (t + 1) * BK);
            asm volatile("s_waitcnt vmcnt(%0)" ::"i"(NA + NB) : "memory");
        } else {
            asm volatile("s_waitcnt vmcnt(0)" ::: "memory");
        }
        __builtin_amdgcn_s_barrier();
        const bf16* la = lds + cur * LD;
        const bf16* lb = la + BM * BK;
#pragma unroll
        for (int kh = 0; kh < 2; kh++) {
            const int cb = kh * 64 + g * 16;
            bf16x8 af[WM], bfv[WN];
#pragma unroll
            for (int mf = 0; mf < WM; mf++) {
                int fr = wr * WM * 16 + mf * 16 + r;
                af[mf] = *(const bf16x8*)&la[fr * 64 + ((cb ^ ((fr & 7) << 4)) >> 1)];
            }
#pragma unroll
            for (int nf = 0; nf < WN; nf++) {
                int fr = wc * WN * 16 + nf * 16 + r;
                bfv[nf] = *(const bf16x8*)&lb[fr * 64 + ((cb ^ ((fr & 7) << 4)) >> 1)];
            }
#pragma unroll
            for (int mf = 0; mf < WM; mf++)
#pragma unroll
                for (int nf = 0; nf < WN; nf++)
                    acc[mf][nf] = MFMA(af[mf], bfv[nf], acc[mf][nf]);
        }
        asm volatile("" ::: "memory");
        __builtin_amdgcn_s_barrier();
        cur ^= 1;
    }

    if (EPI == 0) {
        // ---- coalesced epilogue via LDS tile (reuses buf0: 128*128*2B = 32 KB) ----
        const bool isv = (n0 >= 1024);
        bf16* tile = lds;
#pragma unroll
        for (int mf = 0; mf < WM; mf++)
#pragma unroll
            for (int nf = 0; nf < WN; nf++) {
                int nl = wc * WN * 16 + nf * 16 + r;
                float bv = bias[n0 + nl];
#pragma unroll
                for (int reg = 0; reg < 4; reg++) {
                    int ml = wr * WM * 16 + mf * 16 + g * 4 + reg;
                    bf16 val = (bf16)(acc[mf][nf][reg] + bv);
                    int byte = isv ? (nl * 256 + ((ml * 2) ^ ((nl & 7) << 4)))
                                   : (ml * 256 + ((nl * 2) ^ ((ml & 7) << 4)));
                    tile[byte >> 1] = val;
                }
            }
        __syncthreads();
        const int h0 = (n0 & 511) >> 6;
        if (!isv) {
            // q/k: rows [bh][t][64d] — 16B/lane, 1KB contiguous per wave-instr
            bf16* dst = (n0 < 512) ? o_q : o_k;
#pragma unroll
            for (int j = 0; j < 8; j++) {
                int seg = wave * 64 + j * 8 + (lane >> 3);
                int ml = seg >> 1, hp = seg & 1;
                int m = m0 + ml;
                if (m < 8000) {
                    int cb2 = (hp * 128 + (lane & 7) * 16) ^ ((ml & 7) << 4);
                    bf16x8 v8 = *(const bf16x8*)&tile[(ml * 256 + cb2) >> 1];
                    int b = m / 500, t = m - b * 500;
                    *(bf16x8*)&dst[(((size_t)(b * 8 + h0 + hp)) * 512 + t) * 64 + (lane & 7) * 8] = v8;
                }
            }
        } else {
            // v: rows [bh][d][t] — tile is n-major, read 8 consecutive m (=t)
#pragma unroll
            for (int j = 0; j < 8; j++) {
                int seg = wave * 64 + j * 8 + (lane >> 3);
                int nl = seg >> 1, mh = seg & 1;
                int mloc = mh * 64 + (lane & 7) * 8;
                int m = m0 + mloc;
                if (m < 8000) {
                    int cb2 = (mh * 128 + (lane & 7) * 16) ^ ((nl & 7) << 4);
                    bf16x8 v8 = *(const bf16x8*)&tile[(nl * 256 + cb2) >> 1];
                    int h = h0 + (nl >> 6), d = nl & 63;
                    int b0 = m / 500, b1 = (m + 7) / 500;
                    if (b0 == b1) {
                        int t = m - b0 * 500;
                        bf16* p = o_v + (((size_t)(b0 * 8 + h)) * 64 + d) * 512 + t;
                        if ((t & 7) == 0) {
                            *(bf16x8*)p = v8;
                        } else {  // t % 8 == 4 (odd b): two aligned 8B halves
                            bf16x4 lo = {v8[0], v8[1], v8[2], v8[3]};
                            bf16x4 hi = {v8[4], v8[5], v8[6], v8[7]};
                            *(bf16x4*)p = lo;
                            *(bf16x4*)(p + 4) = hi;
                        }
                    } else {  // run crosses the b*500 boundary: scalar
#pragma unroll
                        for (int i = 0; i < 8; i++) {
                            int mi = m + i;
                            int bb = mi / 500, tt = mi - bb * 500;
                            o_v[(((size_t)(bb * 8 + h)) * 64 + d) * 512 + tt] = v8[i];
                        }
                    }
                }
            }
        }
    } else {
        // proj: direct f32 stores (64B contiguous per 16 lanes)
#pragma unroll
        for (int mf = 0; mf < WM; mf++) {
#pragma unroll
            for (int nf = 0; nf < WN; nf++) {
                int n = n0 + wc * WN * 16 + nf * 16 + r;
                float bv = bias[n];
#pragma unroll
                for (int reg = 0; reg < 4; reg++) {
                    int m = m0 + wr * WM * 16 + mf * 16 + g * 4 + reg;
                    if (m < 8000) o_f[(size_t)m * 512 + n] = acc[mf][nf][reg] + bv;
                }
            }
        }
    }
}

// ---------------- fused attention (+ XCD-chunked swizzle) ----------------
__global__ __launch_bounds__(256) void attn_kernel(const bf16* __restrict__ qb,
                                                   const bf16* __restrict__ kbuf,
                                                   const bf16* __restrict__ vtb,
                                                   const unsigned char* __restrict__ idxg,
                                                   const float* __restrict__ lut,
                                                   bf16* __restrict__ yb) {
    const int lane = threadIdx.x & 63;
    const int wave = threadIdx.x >> 6;
    // 1024 blocks = 8 XCDs x 128: same-bh blocks (sharing K/V/idx) on one XCD
    const int bid0 = blockIdx.x;
    const int wg = (bid0 & 7) * 128 + (bid0 >> 3);
    const int bh = wg >> 3;
    const int qt = wg & 7;
    const int b = bh >> 3;
    const int h = bh & 7;

    __shared__ float lut_s[64];
    __shared__ __align__(16) bf16 P[4][16][72];
    if (threadIdx.x < 64)
        lut_s[threadIdx.x] = (threadIdx.x < 49) ? lut[h * 49 + threadIdx.x] : -1e30f;
    __syncthreads();

    const int r = lane & 15;
    const int ko = (lane >> 4) << 3;
    const int rowbase = qt * 64 + wave * 16;

    const bf16* qp = qb + ((size_t)bh * 512 + rowbase + r) * 64 + ko;
    bf16x8 qf0 = *(const bf16x8*)qp;
    bf16x8 qf1 = *(const bf16x8*)(qp + 32);

    const bf16* kbb = kbuf + (size_t)bh * 512 * 64;
    const bf16* vbb = vtb + (size_t)bh * 64 * 512;
    const unsigned char* idxp = idxg + ((size_t)b * 512 + rowbase + ((lane >> 4) << 2)) * 512;

    f32x4 o[4];
    float m_r[4], l_r[4];
#pragma unroll
    for (int i = 0; i < 4; i++) {
        o[i] = (f32x4){0.f, 0.f, 0.f, 0.f};
        m_r[i] = -1e30f;
        l_r[i] = 0.f;
    }

    const float L2E = 1.4426950408889634f;

    for (int s0 = 0; s0 < 512; s0 += 64) {
        f32x4 sa[4];
#pragma unroll
        for (int nf = 0; nf < 4; nf++) {
            sa[nf] = (f32x4){0.f, 0.f, 0.f, 0.f};
            const bf16* kp = kbb + (size_t)(s0 + nf * 16 + r) * 64 + ko;
            bf16x8 kf0 = *(const bf16x8*)kp;
            bf16x8 kf1 = *(const bf16x8*)(kp + 32);
            sa[nf] = MFMA(qf0, kf0, sa[nf]);
            sa[nf] = MFMA(qf1, kf1, sa[nf]);
        }
#pragma unroll
        for (int nf = 0; nf < 4; nf++) {
            int scol = s0 + nf * 16 + r;
#pragma unroll
            for (int reg = 0; reg < 4; reg++) {
                float biasv = lut_s[idxp[reg * 512 + scol]];
                sa[nf][reg] = fmaf(sa[nf][reg], 0.125f, biasv);
            }
        }
#pragma unroll
        for (int reg = 0; reg < 4; reg++) {
            float mx = fmaxf(fmaxf(sa[0][reg], sa[1][reg]), fmaxf(sa[2][reg], sa[3][reg]));
            mx = fmaxf(mx, __shfl_xor(mx, 1));
            mx = fmaxf(mx, __shfl_xor(mx, 2));
            mx = fmaxf(mx, __shfl_xor(mx, 4));
            mx = fmaxf(mx, __shfl_xor(mx, 8));
            float mnew = fmaxf(m_r[reg], mx);
            float sc = exp2f((m_r[reg] - mnew) * L2E);
            m_r[reg] = mnew;
            float rs = 0.f;
#pragma unroll
            for (int nf = 0; nf < 4; nf++) {
                float p = exp2f((sa[nf][reg] - mnew) * L2E);
                sa[nf][reg] = p;
                rs += p;
            }
            rs += __shfl_xor(rs, 1);
            rs += __shfl_xor(rs, 2);
            rs += __shfl_xor(rs, 4);
            rs += __shfl_xor(rs, 8);
            l_r[reg] = l_r[reg] * sc + rs;
#pragma unroll
            for (int nf = 0; nf < 4; nf++) o[nf][reg] *= sc;
        }
#pragma unroll
        for (int nf = 0; nf < 4; nf++)
#pragma unroll
            for (int reg = 0; reg < 4; reg++)
                P[wave][((lane >> 4) << 2) + reg][nf * 16 + r] = (bf16)sa[nf][reg];
        bf16x8 pf0 = *(const bf16x8*)&P[wave][r][ko];
        bf16x8 pf1 = *(const bf16x8*)&P[wave][r][32 + ko];
#pragma unroll
        for (int nf = 0; nf < 4; nf++) {
            const bf16* vp = vbb + (size_t)(nf * 16 + r) * 512 + s0 + ko;
            bf16x8 vf0 = *(const bf16x8*)vp;
            bf16x8 vf1 = *(const bf16x8*)(vp + 32);
            o[nf] = MFMA(pf0, vf0, o[nf]);
            o[nf] = MFMA(pf1, vf1, o[nf]);
        }
    }
#pragma unroll
    for (int reg = 0; reg < 4; reg++) {
        int t = rowbase + ((lane >> 4) << 2) + reg;
        if (t < 500) {
            float invl = 1.0f / l_r[reg];
            bf16* yp = yb + ((size_t)(b * 500 + t)) * 512 + h * 64;
#pragma unroll
            for (int nf = 0; nf < 4; nf++) yp[nf * 16 + r] = (bf16)(o[nf][reg] * invl);
        }
    }
}

// ---------------- launch ----------------
extern "C" void kernel_launch(void* const* d_in, const int* in_sizes, int n_in,
                              void* d_out, int out_size, void* d_ws, size_t ws_size,
                              hipStream_t stream) {
    const float* x     = (const float*)d_in[0];
    const float* ct    = (const float*)d_in[1];
    const float* Wattn = (const float*)d_in[2];
    const float* battn = (const float*)d_in[3];
    const float* Wproj = (const float*)d_in[4];
    const float* bproj = (const float*)d_in[5];
    const float* lut   = (const float*)d_in[6];
    float* out = (float*)d_out;

    char* w = (char*)d_ws;
    bf16* xb   = (bf16*)w;                w += (size_t)8064 * 512 * 2;
    bf16* Wa_t = (bf16*)w;                w += (size_t)1536 * 512 * 2;
    bf16* Wp_t = (bf16*)w;                w += (size_t)512 * 512 * 2;
    bf16* qb   = (bf16*)w;                w += (size_t)16 * 8 * 512 * 64 * 2;
    bf16* kbuf = (bf16*)w;                w += (size_t)16 * 8 * 512 * 64 * 2;
    bf16* vtb  = (bf16*)w;                w += (size_t)16 * 8 * 64 * 512 * 2;
    unsigned char* idxb = (unsigned char*)w; w += (size_t)16 * 512 * 512;
    bf16* yb   = (bf16*)w;                w += (size_t)8064 * 512 * 2;

    cvt_f32_bf16<<<dim3(2048), 256, 0, stream>>>((const float4*)x, (ushort4*)xb, (8000 * 512) / 4);
    transpose_f32_bf16<<<dim3((512 * 1536 + 255) / 256), 256, 0, stream>>>(Wattn, Wa_t, 512, 1536);
    transpose_f32_bf16<<<dim3((512 * 512 + 255) / 256), 256, 0, stream>>>(Wproj, Wp_t, 512, 512);
    zero_f4<<<dim3(2048), 256, 0, stream>>>((float4*)qb, (3 * 8388608) / 16);
    zero_f4<<<dim3(16), 256, 0, stream>>>((float4*)(xb + (size_t)8000 * 512), 64 * 512 * 2 / 16);
    zero_f4<<<dim3(16), 256, 0, stream>>>((float4*)(yb + (size_t)8000 * 512), 64 * 512 * 2 / 16);
    bucket_kernel<<<dim3(16 * 512), 128, 0, stream>>>(ct, idxb);

    gemm128<128, 2, 2, 0><<<dim3(12, 63), 256, 0, stream>>>(xb, Wa_t, battn, qb, kbuf, vtb, nullptr);

    attn_kernel<<<dim3(1024), 256, 0, stream>>>(qb, kbuf, vtb, idxb, lut, yb);

    gemm128<64, 4, 1, 1><<<dim3(8, 63), 256, 0, stream>>>(yb, Wp_t, bproj, nullptr, nullptr, nullptr, out);
}